// Round 1
// baseline (195.858 us; speedup 1.0000x reference)
//
#include <hip/hip_runtime.h>

// Problem constants (B, C, H, W = 64, 2048, 24, 8; NUM_IDS = 751)
#define BB 64
#define CC 2048
#define HWL 192          // H*W = 24*8
#define NCHUNK 16
#define CCHUNK 128       // CC / NCHUNK

// Kernel 1: partial heat — one block per (b, c-chunk); thread t owns hw position t.
// Coalesced: 192 consecutive floats per c-row.
__global__ void heat_partial_kernel(const float* __restrict__ f,
                                    const float* __restrict__ w,
                                    const int* __restrict__ pids,
                                    float* __restrict__ partial) {
    const int blk = blockIdx.x;
    const int b = blk >> 4;            // / NCHUNK
    const int k = blk & (NCHUNK - 1);  // % NCHUNK
    const int t = threadIdx.x;         // 0..191

    __shared__ float ws[CCHUNK];
    const int row = pids[b];
    if (t < CCHUNK) ws[t] = w[(size_t)row * CC + k * CCHUNK + t];
    __syncthreads();

    const float* fb = f + (size_t)b * CC * HWL + (size_t)k * CCHUNK * HWL;
    float acc = 0.f;
#pragma unroll 8
    for (int c = 0; c < CCHUNK; ++c) {
        acc = fmaf(ws[c], fb[(size_t)c * HWL + t], acc);
    }
    partial[((size_t)(b * NCHUNK) + k) * HWL + t] = acc;
}

// Kernel 2: reduce chunks + min/max normalize per sample. One block per b, 192 threads.
__global__ void heat_norm_kernel(const float* __restrict__ partial,
                                 float* __restrict__ heat) {
    const int b = blockIdx.x;
    const int t = threadIdx.x;  // 0..191
    float v = 0.f;
#pragma unroll
    for (int k = 0; k < NCHUNK; ++k)
        v += partial[((size_t)(b * NCHUNK) + k) * HWL + t];

    __shared__ float vals[HWL];
    __shared__ float s_mn, s_mx;
    vals[t] = v;
    __syncthreads();

    if (t < 64) {
        float a0 = vals[t], a1 = vals[t + 64], a2 = vals[t + 128];
        float mn = fminf(a0, fminf(a1, a2));
        float mx = fmaxf(a0, fmaxf(a1, a2));
        // wave64 butterfly
        for (int off = 32; off > 0; off >>= 1) {
            mn = fminf(mn, __shfl_down(mn, off));
            mx = fmaxf(mx, __shfl_down(mx, off));
        }
        if (t == 0) { s_mn = mn; s_mx = mx; }
    }
    __syncthreads();

    const float mn = s_mn, mx = s_mx;
    // reference: normalize only if max != 0
    const float out = (mx != 0.f) ? (v - mn) / (mx - mn) : v;
    heat[(size_t)b * HWL + t] = out;
}

// Kernel 3: out = features * heat (broadcast over C). float4-vectorized.
__global__ void scale_kernel(const float4* __restrict__ f4,
                             const float4* __restrict__ heat4,
                             float4* __restrict__ out4, int n4) {
    const int i = blockIdx.x * blockDim.x + threadIdx.x;
    if (i >= n4) return;
    const int per_b4 = CC * HWL / 4;   // 98304 vec4 per sample
    const int hw4n = HWL / 4;          // 48
    const int b = i / per_b4;
    const int hw4 = i % hw4n;
    const float4 h = heat4[(size_t)b * hw4n + hw4];
    const float4 v = f4[i];
    out4[i] = make_float4(v.x * h.x, v.y * h.y, v.z * h.z, v.w * h.w);
}

extern "C" void kernel_launch(void* const* d_in, const int* in_sizes, int n_in,
                              void* d_out, int out_size, void* d_ws, size_t ws_size,
                              hipStream_t stream) {
    const float* features = (const float*)d_in[0];   // [64,2048,24,8] f32
    const float* weight   = (const float*)d_in[1];   // [751,2048] f32
    const int*   pids     = (const int*)d_in[2];     // [64] int
    float* out = (float*)d_out;                      // [64,2048,24,8] f32

    float* partial = (float*)d_ws;                     // 64*16*192 floats
    float* heat    = partial + (size_t)BB * NCHUNK * HWL; // 64*192 floats

    heat_partial_kernel<<<BB * NCHUNK, HWL, 0, stream>>>(features, weight, pids, partial);
    heat_norm_kernel<<<BB, HWL, 0, stream>>>(partial, heat);

    const int n4 = BB * CC * HWL / 4;  // 6,291,456
    scale_kernel<<<n4 / 256, 256, 0, stream>>>((const float4*)features,
                                               (const float4*)heat,
                                               (float4*)out, n4);
}

// Round 3
// 195.179 us; speedup vs baseline: 1.0035x; 1.0035x over previous
//
#include <hip/hip_runtime.h>

// Problem constants (B, C, H, W = 64, 2048, 24, 8; NUM_IDS = 751)
#define BB 64
#define CC 2048
#define HWN 192          // H*W
#define HW4 48           // HW in float4
#define NCHUNK 16
#define CCHUNK 128       // CC / NCHUNK  (kernel A chunk)
#define CSLICE 32        // kernel B channel slice
#define NSLICE (CC / CSLICE)  // 64 slices per sample

// ---- Kernel A: partial heat, float4 loads ----
// grid = 1024 (b*16 + k), block = 192. thread -> (cl = tid/48, hw4 = tid%48).
__global__ void __launch_bounds__(192) heat_partial_kernel(
    const float* __restrict__ f,
    const float* __restrict__ w,
    const int* __restrict__ pids,
    float* __restrict__ partial)
{
    const int blk = blockIdx.x;
    const int b = blk >> 4;
    const int k = blk & (NCHUNK - 1);
    const int tid = threadIdx.x;       // 0..191
    const int hw4 = tid % HW4;
    const int cl  = tid / HW4;         // 0..3

    __shared__ float ws[CCHUNK];
    __shared__ __align__(16) float4 red[HWN];

    const int row = pids[b];
    if (tid < CCHUNK) ws[tid] = w[(size_t)row * CC + k * CCHUNK + tid];
    __syncthreads();

    const size_t base = ((size_t)b * CC + (size_t)k * CCHUNK) * HW4;  // float4 units
    const float4* fb4 = (const float4*)f + base;

    float4 acc = make_float4(0.f, 0.f, 0.f, 0.f);
#pragma unroll 8
    for (int c = cl; c < CCHUNK; c += 4) {
        float4 v = fb4[(size_t)c * HW4 + hw4];
        float wv = ws[c];
        acc.x = fmaf(wv, v.x, acc.x);
        acc.y = fmaf(wv, v.y, acc.y);
        acc.z = fmaf(wv, v.z, acc.z);
        acc.w = fmaf(wv, v.w, acc.w);
    }
    red[tid] = acc;
    __syncthreads();
    if (tid < HW4) {
        float4 a0 = red[tid], a1 = red[tid + 48], a2 = red[tid + 96], a3 = red[tid + 144];
        float4 s = make_float4(a0.x + a1.x + a2.x + a3.x,
                               a0.y + a1.y + a2.y + a3.y,
                               a0.z + a1.z + a2.z + a3.z,
                               a0.w + a1.w + a2.w + a3.w);
        ((float4*)partial)[(size_t)(b * NCHUNK + k) * HW4 + tid] = s;
    }
}

// ---- Kernel B: redundant per-block norm + scale ----
// grid = 64*64 = 4096 (b*NSLICE + ck), block = 256.
__global__ void __launch_bounds__(256) norm_scale_kernel(
    const float* __restrict__ f,
    const float* __restrict__ partial,
    float* __restrict__ out)
{
    const int blk = blockIdx.x;
    const int b  = blk / NSLICE;
    const int ck = blk % NSLICE;
    const int tid = threadIdx.x;       // 0..255

    __shared__ __align__(16) float vals[HWN];
    __shared__ __align__(16) float hl[HWN];
    __shared__ float s_mn, s_mx;

    // reduce 16 partial chunks -> heat value at hw position tid (tid < 192)
    float v = 0.f;
    if (tid < HWN) {
        const float* pb = partial + (size_t)b * NCHUNK * HWN + tid;
#pragma unroll
        for (int kk = 0; kk < NCHUNK; ++kk)
            v += pb[(size_t)kk * HWN];
        vals[tid] = v;
    }
    __syncthreads();

    if (tid < 64) {
        float m0 = vals[tid], m1 = vals[tid + 64], m2 = vals[tid + 128];
        float mn = fminf(m0, fminf(m1, m2));
        float mx = fmaxf(m0, fmaxf(m1, m2));
        for (int off = 32; off > 0; off >>= 1) {
            mn = fminf(mn, __shfl_down(mn, off));
            mx = fmaxf(mx, __shfl_down(mx, off));
        }
        if (tid == 0) { s_mn = mn; s_mx = mx; }
    }
    __syncthreads();

    if (tid < HWN) {
        const float mn = s_mn, mx = s_mx;
        // reference: normalize only if max != 0
        hl[tid] = (mx != 0.f) ? (v - mn) / (mx - mn) : v;
    }
    __syncthreads();

    // scale this block's 32-channel slice: 32 * 48 = 1536 float4, 6 per thread
    const size_t base = ((size_t)b * CC + (size_t)ck * CSLICE) * HW4;  // float4 units
    const float4* fb4 = (const float4*)f + base;
    float4* ob4 = (float4*)out + base;
    const float4* h4 = (const float4*)hl;

#pragma unroll
    for (int it = 0; it < (CSLICE * HW4) / 256; ++it) {
        const int idx = it * 256 + tid;        // 0..1535
        const int hw4 = idx % HW4;
        const float4 hv = h4[hw4];
        float4 x = fb4[idx];
        x.x *= hv.x; x.y *= hv.y; x.z *= hv.z; x.w *= hv.w;
        ob4[idx] = x;
    }
}

extern "C" void kernel_launch(void* const* d_in, const int* in_sizes, int n_in,
                              void* d_out, int out_size, void* d_ws, size_t ws_size,
                              hipStream_t stream) {
    const float* features = (const float*)d_in[0];   // [64,2048,24,8] f32
    const float* weight   = (const float*)d_in[1];   // [751,2048] f32
    const int*   pids     = (const int*)d_in[2];     // [64] int
    float* out = (float*)d_out;                      // [64,2048,24,8] f32
    float* partial = (float*)d_ws;                   // 64*16*192 floats

    heat_partial_kernel<<<BB * NCHUNK, HWN, 0, stream>>>(features, weight, pids, partial);
    norm_scale_kernel<<<BB * NSLICE, 256, 0, stream>>>(features, partial, out);
}